// Round 6
// baseline (531.884 us; speedup 1.0000x reference)
//
#include <hip/hip_runtime.h>

// ---------------- constants ----------------
#define BB   16
#define TT   512
#define CC   1024
#define DD   4096
#define NN   (BB*TT)        // 8192
#define NWIN 127
#define KTOP 128

typedef __attribute__((ext_vector_type(8))) unsigned short ushort8;
typedef _Float16 half8 __attribute__((ext_vector_type(8)));
typedef __attribute__((ext_vector_type(4))) float f32x4;

// ---------------- helpers ----------------
__device__ __forceinline__ unsigned short f2h(float f) {
    union { _Float16 h; unsigned short u; } c;
    c.h = (_Float16)f;   // RNE
    return c.u;
}
__device__ __forceinline__ float h2f(unsigned short u) {
    union { unsigned short u; _Float16 h; } c;
    c.u = u;
    return (float)c.h;
}
__device__ __forceinline__ unsigned tokey(float f) {
    unsigned u = __float_as_uint(f);
    return (u & 0x80000000u) ? ~u : (u | 0x80000000u);
}
__device__ __forceinline__ void async_lds16(const void* g, void* l) {
    __builtin_amdgcn_global_load_lds((const __attribute__((address_space(1))) void*)g,
                                     (__attribute__((address_space(3))) void*)l, 16, 0, 0);
}

#define GATE() do { __builtin_amdgcn_sched_barrier(0); \
                    asm volatile("s_waitcnt vmcnt(0)" ::: "memory"); \
                    __builtin_amdgcn_s_barrier(); \
                    __builtin_amdgcn_sched_barrier(0); } while (0)

// wave-level scans (64 lanes)
__device__ __forceinline__ unsigned wave_prefix_incl(unsigned v) {
    int lane = threadIdx.x & 63;
#pragma unroll
    for (int off = 1; off < 64; off <<= 1) {
        unsigned n = __shfl_up(v, off, 64);
        if (lane >= off) v += n;
    }
    return v;
}
__device__ __forceinline__ unsigned wave_suffix_incl(unsigned v) {
    int lane = threadIdx.x & 63;
#pragma unroll
    for (int off = 1; off < 64; off <<= 1) {
        unsigned n = __shfl_down(v, off, 64);
        if (lane + off < 64) v += n;
    }
    return v;
}

// ---------------- top-128 radix select (dense, used by winsum) ----------------
__device__ __forceinline__ unsigned select_top128(const unsigned* keys,
                                                  unsigned* hist, unsigned* shx) {
    const int tid = threadIdx.x, wid = tid >> 6, lane = tid & 63;
    const unsigned ZKEY = 0x80000000u;
    unsigned cpos = 0, cz = 0;
#pragma unroll
    for (int i = 0; i < 16; ++i) {
        cpos += (keys[i] > ZKEY);
        cz   += (keys[i] == ZKEY);
    }
    unsigned ppos = wave_prefix_incl(cpos);
    unsigned pz   = wave_prefix_incl(cz);
    if (lane == 63) { shx[wid] = ppos; shx[4 + wid] = pz; }
    __syncthreads();
    unsigned nz = shx[0] + shx[1] + shx[2] + shx[3];
    unsigned selbits = 0u;
    if (nz <= KTOP) {
        unsigned need = KTOP - nz;
        unsigned zr = pz - cz;
        if (wid > 0) zr += shx[4];
        if (wid > 1) zr += shx[5];
        if (wid > 2) zr += shx[6];
#pragma unroll
        for (int i = 0; i < 16; ++i) {
            bool sel = (keys[i] > ZKEY) || (keys[i] == ZKEY && zr < need);
            if (keys[i] == ZKEY) ++zr;
            selbits |= (sel ? 1u : 0u) << i;
        }
        return selbits;
    }
    unsigned k2[16];
#pragma unroll
    for (int i = 0; i < 16; ++i) k2[i] = (keys[i] > ZKEY) ? keys[i] : 0u;
    unsigned prefix = 0u, pmask = 0u, Kr = KTOP;
    for (int shift = 24; shift >= 0; shift -= 8) {
        hist[tid] = 0u; hist[256 + tid] = 0u; hist[512 + tid] = 0u; hist[768 + tid] = 0u;
        __syncthreads();
        unsigned* h = hist + (wid << 8);
#pragma unroll
        for (int i = 0; i < 16; ++i)
            if (k2[i] && (k2[i] & pmask) == prefix) atomicAdd(&h[(k2[i] >> shift) & 255u], 1u);
        __syncthreads();
        unsigned v = hist[tid] + hist[256 + tid] + hist[512 + tid] + hist[768 + tid];
        unsigned s = wave_suffix_incl(v);
        if (lane == 0) shx[wid] = s;
        __syncthreads();
        unsigned stot = s;
        if (wid == 0) stot += shx[1] + shx[2] + shx[3];
        else if (wid == 1) stot += shx[2] + shx[3];
        else if (wid == 2) stot += shx[3];
        unsigned above = stot - v;
        if (stot >= Kr && above < Kr) { shx[8] = (unsigned)tid; shx[9] = Kr - above; }
        __syncthreads();
        prefix |= shx[8] << shift;
        pmask |= 0xFFu << shift;
        Kr = shx[9];
    }
    unsigned T = prefix, need = Kr;
    unsigned ce = 0;
#pragma unroll
    for (int i = 0; i < 16; ++i) ce += (k2[i] == T);
    unsigned pe = wave_prefix_incl(ce);
    __syncthreads();
    if (lane == 63) shx[4 + wid] = pe;
    __syncthreads();
    unsigned er = pe - ce;
    if (wid > 0) er += shx[4];
    if (wid > 1) er += shx[5];
    if (wid > 2) er += shx[6];
#pragma unroll
    for (int i = 0; i < 16; ++i) {
        bool sel = (k2[i] > T) || (k2[i] == T && er < need);
        if (k2[i] == T) ++er;
        selbits |= (sel ? 1u : 0u) << i;
    }
    return selbits;
}

// ---------------- merged converts + pooled/sae zeroing ----------------
__global__ __launch_bounds__(256) void k_convert_all(const float* __restrict__ x,
                                                     const float* __restrict__ Wenc,
                                                     const float* __restrict__ Wdec,
                                                     const float* __restrict__ bdec,
                                                     unsigned short* __restrict__ xh,
                                                     unsigned short* __restrict__ wh,
                                                     unsigned short* __restrict__ wdh,
                                                     float* __restrict__ pooled_zero) {
    const int bid = blockIdx.x;
    if (bid < 8192) {
        size_t i = (size_t)bid * 256 + threadIdx.x;       // x: 2M float4s
        float4 v = ((const float4*)x)[i];
        size_t c = (i * 4) & (CC - 1);
        v.x -= bdec[c]; v.y -= bdec[c + 1]; v.z -= bdec[c + 2]; v.w -= bdec[c + 3];
        uint2 o;
        o.x = (unsigned)f2h(v.x) | ((unsigned)f2h(v.y) << 16);
        o.y = (unsigned)f2h(v.z) | ((unsigned)f2h(v.w) << 16);
        ((uint2*)xh)[i] = o;
    } else if (bid < 12288) {
        size_t i = (size_t)(bid - 8192) * 256 + threadIdx.x;  // Wenc: 1M float4s
        float4 v = ((const float4*)Wenc)[i];
        uint2 o;
        o.x = (unsigned)f2h(v.x) | ((unsigned)f2h(v.y) << 16);
        o.y = (unsigned)f2h(v.z) | ((unsigned)f2h(v.w) << 16);
        ((uint2*)wh)[i] = o;
    } else if (bid < 16384) {
        size_t i = (size_t)(bid - 12288) * 256 + threadIdx.x; // Wdec: 1M float4s -> fp16
        float4 v = ((const float4*)Wdec)[i];
        uint2 o;
        o.x = (unsigned)f2h(v.x) | ((unsigned)f2h(v.y) << 16);
        o.y = (unsigned)f2h(v.z) | ((unsigned)f2h(v.w) << 16);
        ((uint2*)wdh)[i] = o;
    } else {
        const int n4 = (BB * DD + 64) / 4;
        for (int i = threadIdx.x; i < n4; i += 256)
            ((float4*)pooled_zero)[i] = make_float4(0.f, 0.f, 0.f, 0.f);
    }
}

// ---------------- 8-wave B staging, XOR-swizzled, RAW block base ----------------
// LDS[r][cg] = G[r][cg ^ (r&7)]; readers XOR column-group with (row&7).
__device__ __forceinline__ void stage256(const unsigned short* gbase, size_t ldk,
                                         unsigned short* lds, int w, int lane) {
    const int sub = lane >> 3;
    const int cj  = (lane & 7) ^ sub;
#pragma unroll
    for (int i = 0; i < 4; ++i) {
        int n = w * 4 + i;            // 0..31
        int r = n * 8 + sub;          // 0..255
        async_lds16(gbase + (size_t)r * ldk + cj * 8, lds + n * 512);
    }
}
__device__ __forceinline__ void stage128(const unsigned short* gbase, size_t ldk,
                                         unsigned short* lds, int w, int lane) {
    const int sub = lane >> 3;
    const int cj  = (lane & 7) ^ sub;
#pragma unroll
    for (int i = 0; i < 2; ++i) {
        int n = w * 2 + i;            // 0..15
        int r = n * 8 + sub;          // 0..127
        async_lds16(gbase + (size_t)r * ldk + cj * 8, lds + n * 512);
    }
}

// =====================================================================
// GEMM1: 256x256 tile, BK=64, 8 waves (4M x 2N, wave tile 64x128).
// A operand loaded DIRECT global->reg (L2-resident, depth-1 prefetch);
// only B staged in LDS (2 bufs x 32KB = 64KB).
// One vmcnt(0)+barrier gate per K-tile. Bit-identical accumulation order.
// =====================================================================
__global__ __launch_bounds__(512, 2) void k_gemm_enc_256(const unsigned short* __restrict__ Ah,
                                                         const unsigned short* __restrict__ Bh,
                                                         const float* __restrict__ bias,
                                                         unsigned short* __restrict__ Cout,
                                                         float* __restrict__ gsum) {
    __shared__ __align__(16) unsigned short Bt[2][2][128 * 64];  // 64 KB (2 bufs x 256 rows)
    const int tid = threadIdx.x, w = tid >> 6, lane = tid & 63;
    const int bm = blockIdx.y * 256, bn = blockIdx.x * 256;
    const int wr = w >> 1, wc = w & 1;          // 4M x 2N
    const int rA = lane & 15, q = lane >> 4;
    const int sc0 = (q ^ (rA & 7)) << 3, sc1 = ((4 + q) ^ (rA & 7)) << 3;
    const unsigned short* Braw = Bh + (size_t)bn * 1024;           // raw block base
    const unsigned short* Agp  = Ah + ((size_t)(bm + wr * 64 + rA)) * 1024 + q * 8;

    half8 aE[4][2], aO[4][2];
    f32x4 acc[4][8] = {};

    auto LDA = [&](half8 (&dst)[4][2], int kt) {
        const unsigned short* g = Agp + (kt << 6);
#pragma unroll
        for (int mf = 0; mf < 4; ++mf)
#pragma unroll
            for (int kk = 0; kk < 2; ++kk)
                dst[mf][kk] = *(const half8*)(g + (size_t)mf * 16 * 1024 + kk * 32);
    };
    auto STAGEB = [&](int kt, unsigned short* buf) {
        stage256(Braw + (kt << 6), 1024, buf, w, lane);   // all 256 rows x 64 cols
    };
    auto CL = [&](half8 (&aC)[4][2], const unsigned short* rb, int c) {
        half8 b[2][2];
#pragma unroll
        for (int j = 0; j < 2; ++j) {
            const unsigned short* p = rb + ((2 * c + j) * 16 + rA) * 64;
            b[j][0] = *(const half8*)(p + sc0);
            b[j][1] = *(const half8*)(p + sc1);
        }
        __builtin_amdgcn_s_setprio(1);
#pragma unroll
        for (int kk = 0; kk < 2; ++kk)
#pragma unroll
            for (int mf = 0; mf < 4; ++mf)
#pragma unroll
                for (int j = 0; j < 2; ++j)
                    acc[mf][2 * c + j] = __builtin_amdgcn_mfma_f32_16x16x32_f16(
                        aC[mf][kk], b[j][kk], acc[mf][2 * c + j], 0, 0, 0);
        __builtin_amdgcn_s_setprio(0);
    };

    // prologue: A(0)->aE, B(0)->buf0
    LDA(aE, 0);
    STAGEB(0, &Bt[0][0][0]);

#pragma unroll 1
    for (int i = 0; i < 8; ++i) {
        const int t0 = 2 * i, t1 = 2 * i + 1;
        // even tile t0: compute aE from buf[0], prefetch t0+1 into aO/buf[1]
        GATE();
        { LDA(aO, t0 + 1); STAGEB(t0 + 1, &Bt[1][0][0]); }
        __builtin_amdgcn_sched_barrier(0);
        {
            const unsigned short* rb = &Bt[0][wc][0];
            CL(aE, rb, 0); CL(aE, rb, 1); CL(aE, rb, 2); CL(aE, rb, 3);
        }
        // odd tile t1: compute aO from buf[1], prefetch t1+1 into aE/buf[0]
        GATE();
        if (t1 + 1 < 16) { LDA(aE, t1 + 1); STAGEB(t1 + 1, &Bt[0][0][0]); }
        __builtin_amdgcn_sched_barrier(0);
        {
            const unsigned short* rb = &Bt[1][wc][0];
            CL(aO, rb, 0); CL(aO, rb, 1); CL(aO, rb, 2); CL(aO, rb, 3);
        }
    }

    // ---------------- epilogue: 4 passes of 64 rows through 64KB cbuf ----------------
    __syncthreads();
    float* cbuf = (float*)&Bt[0][0][0];   // [64][256] fp32, XOR-swizzled
    const int cl = rA, qr = q * 4;
    float bv[8];
#pragma unroll
    for (int nf = 0; nf < 8; ++nf) bv[nf] = bias[bn + wc * 128 + nf * 16 + cl];
    const int rg = tid >> 5, seg = tid & 31;   // 16 row-groups x 32 col-segs
#pragma unroll 1
    for (int p = 0; p < 4; ++p) {
        if (p) __syncthreads();
        if (wr == p) {
#pragma unroll
            for (int mf = 0; mf < 4; ++mf) {
#pragma unroll
                for (int nf = 0; nf < 8; ++nf) {
                    int col = wc * 128 + nf * 16 + cl;
#pragma unroll
                    for (int r = 0; r < 4; ++r) {
                        int lrow = mf * 16 + qr + r;
                        float v = acc[mf][nf][r] + bv[nf];
                        v = v > 0.f ? v : 0.f;
                        cbuf[lrow * 256 + (col ^ (((lrow >> 2) & 7) << 2))] = v;
                    }
                }
            }
        }
        __syncthreads();
        f32x4 gs0 = {}, gs1 = {};
#pragma unroll
        for (int i2 = 0; i2 < 4; ++i2) {
            const int lrow = rg * 4 + i2;
            const f32x4* crow = (const f32x4*)cbuf + lrow * 64;
            const int s = (lrow >> 2) & 7;
            f32x4 v0 = crow[(seg * 2 + 0) ^ s];
            f32x4 v1 = crow[(seg * 2 + 1) ^ s];
            uint4 o;
            o.x = (unsigned)f2h(v0[0]) | ((unsigned)f2h(v0[1]) << 16);
            o.y = (unsigned)f2h(v0[2]) | ((unsigned)f2h(v0[3]) << 16);
            o.z = (unsigned)f2h(v1[0]) | ((unsigned)f2h(v1[1]) << 16);
            o.w = (unsigned)f2h(v1[2]) | ((unsigned)f2h(v1[3]) << 16);
            *(uint4*)&Cout[(size_t)(bm + p * 64 + lrow) * 4096 + bn + seg * 8] = o;
            gs0 += v0; gs1 += v1;
        }
        if (gsum) {
            size_t gr = ((size_t)(bm >> 2) + p * 16 + rg) * 4096 + bn + seg * 8;
            *(f32x4*)&gsum[gr + 0] = gs0;
            *(f32x4*)&gsum[gr + 4] = gs1;
        }
    }
}

// =====================================================================
// GEMM2: 256x128 tile, BK=64, 8 waves (4M x 2N, wave tile 64x64).
// A (= post, fp16) direct global->reg; B (wd16) staged in LDS (32KB).
// One gate per K-tile (64 tiles). recon + fused sae loss.
// =====================================================================
__global__ __launch_bounds__(512, 2) void k_gemm_recon_256(const unsigned short* __restrict__ Ap,
                                                           const unsigned short* __restrict__ Bp,
                                                           const float* __restrict__ bdec,
                                                           const float* __restrict__ X,
                                                           float* __restrict__ sae) {
    __shared__ __align__(16) unsigned short Bt[2][128 * 64];   // 32 KB
    __shared__ float red[512];
    const int tid = threadIdx.x, w = tid >> 6, lane = tid & 63;
    const int bm = blockIdx.y * 256, bn = blockIdx.x * 128;
    const int wr = w >> 1, wc = w & 1;          // 4M x 2N
    const int rA = lane & 15, q = lane >> 4;
    const int sc0 = (q ^ (rA & 7)) << 3, sc1 = ((4 + q) ^ (rA & 7)) << 3;
    const unsigned short* Braw = Bp + (size_t)bn * 4096;          // raw block base
    const unsigned short* Agp  = Ap + ((size_t)(bm + wr * 64 + rA)) * 4096 + q * 8;

    half8 aE[4][2], aO[4][2];
    f32x4 acc[4][4] = {};

    auto LDA = [&](half8 (&dst)[4][2], int kt) {
        const unsigned short* g = Agp + (kt << 6);
#pragma unroll
        for (int mf = 0; mf < 4; ++mf)
#pragma unroll
            for (int kk = 0; kk < 2; ++kk)
                dst[mf][kk] = *(const half8*)(g + (size_t)mf * 16 * 4096 + kk * 32);
    };
    auto CL = [&](half8 (&aC)[4][2], const unsigned short* rb, int c) {
        half8 b[2][2];
#pragma unroll
        for (int j = 0; j < 2; ++j) {
            const unsigned short* p = rb + (wc * 64 + (2 * c + j) * 16 + rA) * 64;
            b[j][0] = *(const half8*)(p + sc0);
            b[j][1] = *(const half8*)(p + sc1);
        }
        __builtin_amdgcn_s_setprio(1);
#pragma unroll
        for (int kk = 0; kk < 2; ++kk)
#pragma unroll
            for (int mf = 0; mf < 4; ++mf)
#pragma unroll
                for (int j = 0; j < 2; ++j)
                    acc[mf][2 * c + j] = __builtin_amdgcn_mfma_f32_16x16x32_f16(
                        aC[mf][kk], b[j][kk], acc[mf][2 * c + j], 0, 0, 0);
        __builtin_amdgcn_s_setprio(0);
    };

    LDA(aE, 0);
    stage128(Braw, 4096, &Bt[0][0], w, lane);

#pragma unroll 1
    for (int i = 0; i < 32; ++i) {
        const int t0 = 2 * i, t1 = 2 * i + 1;
        GATE();
        { LDA(aO, t0 + 1); stage128(Braw + ((t0 + 1) << 6), 4096, &Bt[1][0], w, lane); }
        __builtin_amdgcn_sched_barrier(0);
        { const unsigned short* rb = &Bt[0][0]; CL(aE, rb, 0); CL(aE, rb, 1); }
        GATE();
        if (t1 + 1 < 64) { LDA(aE, t1 + 1); stage128(Braw + ((t1 + 1) << 6), 4096, &Bt[0][0], w, lane); }
        __builtin_amdgcn_sched_barrier(0);
        { const unsigned short* rb = &Bt[1][0]; CL(aO, rb, 0); CL(aO, rb, 1); }
    }

    // ---------------- epilogue: fused sae ----------------
    const int cl = rA, qr = q * 4;
    float lsum = 0.f;
#pragma unroll
    for (int mf = 0; mf < 4; ++mf) {
        int row0 = bm + wr * 64 + mf * 16 + qr;
#pragma unroll
        for (int nf = 0; nf < 4; ++nf) {
            int col = bn + wc * 64 + nf * 16 + cl;
            float bvv = bdec[col];
#pragma unroll
            for (int r = 0; r < 4; ++r) {
                float v = acc[mf][nf][r] + bvv - X[(size_t)(row0 + r) * 1024 + col];
                lsum += v * v;
            }
        }
    }
    red[tid] = lsum;
    __syncthreads();
    for (int s = 256; s > 0; s >>= 1) { if (tid < s) red[tid] += red[tid + s]; __syncthreads(); }
    if (tid == 0) atomicAdd(sae, red[0]);
}

// ---------------- window top-128 from fused group sums ----------------
__global__ __launch_bounds__(256) void k_winsum_g(const float* __restrict__ gsum,
                                                  unsigned* __restrict__ wmask) {
    __shared__ unsigned hist[1024];
    __shared__ unsigned shx[16];
    __shared__ unsigned short halves[256];
    const int tid = threadIdx.x, w = blockIdx.x, b = blockIdx.y;
    const float* g0 = gsum + ((size_t)(b * 128 + w)) * DD + tid * 16;
    const float* g1 = g0 + DD;
    unsigned keys[16];
#pragma unroll
    for (int q = 0; q < 4; ++q) {
        float4 u = *(const float4*)(g0 + q * 4);
        float4 v = *(const float4*)(g1 + q * 4);
        keys[q * 4 + 0] = tokey(u.x + v.x);
        keys[q * 4 + 1] = tokey(u.y + v.y);
        keys[q * 4 + 2] = tokey(u.z + v.z);
        keys[q * 4 + 3] = tokey(u.w + v.w);
    }
    unsigned selbits = select_top128(keys, hist, shx);
    halves[tid] = (unsigned short)selbits;
    __syncthreads();
    if (tid < 128)
        wmask[(size_t)(b * NWIN + w) * 128 + tid] =
            (unsigned)halves[2 * tid] | ((unsigned)halves[2 * tid + 1] << 16);
}

// fallback: window sums read from fp16 post directly (if ws too small for gsum)
__global__ __launch_bounds__(256) void k_winsum_p(const unsigned short* __restrict__ post,
                                                  unsigned* __restrict__ wmask) {
    __shared__ unsigned hist[1024];
    __shared__ unsigned shx[16];
    __shared__ unsigned short halves[256];
    const int tid = threadIdx.x, w = blockIdx.x, b = blockIdx.y;
    const unsigned short* base = post + (size_t)(b * TT + w * 4) * DD + tid * 16;
    float s[16] = {};
#pragma unroll
    for (int j = 0; j < 8; ++j) {
        const unsigned short* rp = base + (size_t)j * DD;
        ushort8 u0 = *(const ushort8*)rp;
        ushort8 u1 = *(const ushort8*)(rp + 8);
#pragma unroll
        for (int i = 0; i < 8; ++i) { s[i] += h2f(u0[i]); s[8 + i] += h2f(u1[i]); }
    }
    unsigned keys[16];
#pragma unroll
    for (int i = 0; i < 16; ++i) keys[i] = tokey(s[i]);
    unsigned selbits = select_top128(keys, hist, shx);
    halves[tid] = (unsigned short)selbits;
    __syncthreads();
    if (tid < 128)
        wmask[(size_t)(b * NWIN + w) * 128 + tid] =
            (unsigned)halves[2 * tid] | ((unsigned)halves[2 * tid + 1] << 16);
}

// ---------------- votes: 4 rows per block (shared masks), radix top-128 ----------------
__global__ __launch_bounds__(256) void k_votes(unsigned short* __restrict__ post,
                                               const unsigned* __restrict__ wmask,
                                               float* __restrict__ pooled) {
    __shared__ unsigned long long cand[256];
    __shared__ unsigned char selbyte[DD];
    __shared__ unsigned shx[16];
    __shared__ unsigned hcnt[256];
    const int tid = threadIdx.x, wid = tid >> 6, lane = tid & 63;
    const int g = blockIdx.x, b = blockIdx.y;
    int w1 = g, w0 = g - 1;
    unsigned mw0 = 0u, mw1 = 0u;
    if (w0 >= 0)        mw0 = wmask[(size_t)(b * NWIN + w0) * 128 + (tid >> 1)];
    if (w1 <= NWIN - 1) mw1 = wmask[(size_t)(b * NWIN + w1) * 128 + (tid >> 1)];
    const int bbase = (tid & 1) * 16;
    const unsigned ZKEY = 0x80000000u;
    float psum[16];
#pragma unroll
    for (int i = 0; i < 16; ++i) psum[i] = 0.f;

    for (int r = 0; r < 4; ++r) {
        unsigned short* rp = post + (size_t)(b * TT + g * 4 + r) * DD;
        ushort8 raw0 = *(const ushort8*)(rp + tid * 16);
        ushort8 raw1 = *(const ushort8*)(rp + tid * 16 + 8);
        float vals[16];
#pragma unroll
        for (int i = 0; i < 8; ++i) { vals[i] = h2f(raw0[i]); vals[8 + i] = h2f(raw1[i]); }
        unsigned keys[16];
#pragma unroll
        for (int i = 0; i < 16; ++i) {
            float cov = (float)(((mw0 >> (bbase + i)) & 1u) + ((mw1 >> (bbase + i)) & 1u));
            keys[i] = tokey(vals[i] * cov);
        }
        unsigned cpos = 0, cz = 0;
#pragma unroll
        for (int i = 0; i < 16; ++i) {
            cpos += (keys[i] > ZKEY);
            cz   += (keys[i] == ZKEY);
        }
        unsigned ppos = wave_prefix_incl(cpos);
        unsigned pz   = wave_prefix_incl(cz);
        __syncthreads();   // protect shx/selbyte from previous row before reuse
        if (lane == 63) { shx[wid] = ppos; shx[4 + wid] = pz; }
        __syncthreads();
        unsigned nz = shx[0] + shx[1] + shx[2] + shx[3];
        unsigned selbits = 0u;
        if (nz <= KTOP) {
            unsigned need = KTOP - nz;
            unsigned zr = pz - cz;
            if (wid > 0) zr += shx[4];
            if (wid > 1) zr += shx[5];
            if (wid > 2) zr += shx[6];
#pragma unroll
            for (int i = 0; i < 16; ++i) {
                bool sel = (keys[i] > ZKEY) || (keys[i] == ZKEY && zr < need);
                if (keys[i] == ZKEY) ++zr;
                selbits |= (sel ? 1u : 0u) << i;
            }
        } else {
            *(uint4*)(selbyte + tid * 16) = make_uint4(0u, 0u, 0u, 0u);
            unsigned off = ppos - cpos;
            if (wid > 0) off += shx[0];
            if (wid > 1) off += shx[1];
            if (wid > 2) off += shx[2];
#pragma unroll
            for (int i = 0; i < 16; ++i) {
                if (keys[i] > ZKEY && off < 256u) {
                    int d = tid * 16 + i;
                    cand[off++] = ((unsigned long long)keys[i] << 12) | (unsigned)(4095 - d);
                }
            }
            __syncthreads();
            const unsigned m = nz < 256u ? nz : 256u;
            unsigned long long ek = (tid < (int)m) ? cand[tid] : 0ULL;
            unsigned Kr = KTOP;
            bool alive = (tid < (int)m);
            bool sel = false;
#pragma unroll
            for (int pass = 0; pass < 3; ++pass) {
                const int shift = 36 - pass * 8;
                hcnt[tid] = 0u;
                __syncthreads();
                unsigned dg = (unsigned)(ek >> shift) & 255u;
                if (alive) atomicAdd(&hcnt[dg], 1u);
                __syncthreads();
                unsigned v = hcnt[tid];
                unsigned s = wave_suffix_incl(v);
                if (lane == 0) shx[8 + wid] = s;
                __syncthreads();
                unsigned stot = s;
                if (wid == 0) stot += shx[9] + shx[10] + shx[11];
                else if (wid == 1) stot += shx[10] + shx[11];
                else if (wid == 2) stot += shx[11];
                unsigned above = stot - v;
                if (stot >= Kr && above < Kr) { shx[12] = (unsigned)tid; shx[13] = Kr - above; }
                __syncthreads();
                unsigned Td = shx[12];
                Kr = shx[13];
                if (alive) {
                    if (dg > Td) { sel = true; alive = false; }
                    else if (dg < Td) alive = false;
                }
            }
            unsigned av = alive ? 1u : 0u;
            unsigned pa = wave_prefix_incl(av);
            if (lane == 63) shx[8 + wid] = pa;
            __syncthreads();
            unsigned er = pa - av;
            if (wid > 0) er += shx[8];
            if (wid > 1) er += shx[9];
            if (wid > 2) er += shx[10];
            if (alive && er < Kr) sel = true;
            if (sel) selbyte[4095 - (unsigned)(ek & 0xFFFu)] = 1;
            __syncthreads();
#pragma unroll
            for (int i = 0; i < 16; ++i)
                selbits |= (selbyte[tid * 16 + i] ? 1u : 0u) << i;
        }
        ushort8 o0, o1;
#pragma unroll
        for (int i = 0; i < 8; ++i) {
            bool s0 = (selbits >> i) & 1u;
            bool s1 = (selbits >> (8 + i)) & 1u;
            o0[i] = s0 ? raw0[i] : (unsigned short)0;
            o1[i] = s1 ? raw1[i] : (unsigned short)0;
            if (s0) psum[i]     += vals[i];
            if (s1) psum[8 + i] += vals[8 + i];
        }
        *(ushort8*)(rp + tid * 16)     = o0;
        *(ushort8*)(rp + tid * 16 + 8) = o1;
    }
#pragma unroll
    for (int i = 0; i < 16; ++i)
        if (psum[i] != 0.f) atomicAdd(&pooled[(size_t)b * DD + tid * 16 + i], psum[i]);
}

// ---------------- head ----------------
__device__ __forceinline__ float block_sum(float v, float* red) {
    const int tid = threadIdx.x;
    red[tid] = v;
    __syncthreads();
    for (int s = 128; s > 0; s >>= 1) { if (tid < s) red[tid] += red[tid + s]; __syncthreads(); }
    float r = red[0];
    __syncthreads();
    return r;
}

__global__ __launch_bounds__(256) void k_head_ln(const float* __restrict__ pooled,
                                                 const float* __restrict__ lng,
                                                 const float* __restrict__ lnb,
                                                 float* __restrict__ lnout) {
    __shared__ float red[256];
    const int b = blockIdx.x, tid = threadIdx.x;
    float pv[16];
    float s = 0.f;
#pragma unroll
    for (int q = 0; q < 4; ++q) {
        float4 u = *(const float4*)(pooled + (size_t)b * DD + tid * 16 + q * 4);
        pv[q * 4 + 0] = u.x * (1.f / TT); pv[q * 4 + 1] = u.y * (1.f / TT);
        pv[q * 4 + 2] = u.z * (1.f / TT); pv[q * 4 + 3] = u.w * (1.f / TT);
        s += pv[q * 4 + 0] + pv[q * 4 + 1] + pv[q * 4 + 2] + pv[q * 4 + 3];
    }
    float mean = block_sum(s, red) * (1.f / (float)DD);
    float vs = 0.f;
#pragma unroll
    for (int i = 0; i < 16; ++i) { float c = pv[i] - mean; vs += c * c; }
    float var = block_sum(vs, red) * (1.f / (float)DD);
    float inv = rsqrtf(var + 1e-5f);
#pragma unroll
    for (int q = 0; q < 4; ++q) {
        float4 g = *(const float4*)(lng + tid * 16 + q * 4);
        float4 bb = *(const float4*)(lnb + tid * 16 + q * 4);
        float4 o;
        o.x = (pv[q * 4 + 0] - mean) * inv * g.x + bb.x;
        o.y = (pv[q * 4 + 1] - mean) * inv * g.y + bb.y;
        o.z = (pv[q * 4 + 2] - mean) * inv * g.z + bb.z;
        o.w = (pv[q * 4 + 3] - mean) * inv * g.w + bb.w;
        *(float4*)(lnout + (size_t)b * DD + tid * 16 + q * 4) = o;
    }
}

__global__ __launch_bounds__(256) void k_head_mlp(const float* __restrict__ lnout,
                                                  const float* __restrict__ W1,
                                                  const float* __restrict__ b1,
                                                  float* __restrict__ h) {
    const int gw = (blockIdx.x * 256 + threadIdx.x) >> 6;   // 0..4095
    const int lane = threadIdx.x & 63;
    const int b = gw >> 8, row = gw & 255;
    const float* lp = lnout + (size_t)b * DD;
    const float* wr = W1 + (size_t)row * DD;
    float a = 0.f;
#pragma unroll
    for (int k = 0; k < DD / 64; ++k)
        a += lp[lane + 64 * k] * wr[lane + 64 * k];
#pragma unroll
    for (int off = 32; off > 0; off >>= 1) a += __shfl_down(a, off, 64);
    if (lane == 0) h[b * 256 + row] = fmaxf(a + b1[row], 0.f);
}

__global__ __launch_bounds__(256) void k_head_out(const float* __restrict__ h,
                                                  const float* __restrict__ W2,
                                                  const float* __restrict__ b2,
                                                  const float* __restrict__ sae,
                                                  float* __restrict__ out) {
    __shared__ float red[256];
    const int b = blockIdx.x, tid = threadIdx.x;
    float hv = h[b * 256 + tid];
    float l0 = block_sum(hv * W2[tid], red) + b2[0];
    float l1 = block_sum(hv * W2[256 + tid], red) + b2[1];
    if (tid == 0) {
        float m = fmaxf(l0, l1);
        float lse = m + logf(expf(l0 - m) + expf(l1 - m));
        out[2 * b] = l0 - lse;
        out[2 * b + 1] = l1 - lse;
        if (b == 0) out[32] = sae[0] * (1.f / (float)((size_t)NN * CC));
    }
}

// ---------------- launch ----------------
extern "C" void kernel_launch(void* const* d_in, const int* in_sizes, int n_in,
                              void* d_out, int out_size, void* d_ws, size_t ws_size,
                              hipStream_t stream) {
    const float* x    = (const float*)d_in[0];
    const float* Wenc = (const float*)d_in[1];
    const float* benc = (const float*)d_in[2];
    const float* Wdec = (const float*)d_in[3];
    const float* bdec = (const float*)d_in[4];
    const float* lng  = (const float*)d_in[5];
    const float* lnb  = (const float*)d_in[6];
    const float* W1   = (const float*)d_in[7];
    const float* b1   = (const float*)d_in[8];
    const float* W2   = (const float*)d_in[9];
    const float* b2   = (const float*)d_in[10];
    float* out = (float*)d_out;

    char* ws = (char*)d_ws;
    unsigned short* post  = (unsigned short*)(ws + 0);           //  67,108,864 (fp16 post / masked in place)
    unsigned short* xh16  = (unsigned short*)(ws + 67108864);    //  16,777,216 (fp16 x - b_dec; dead after gemm1)
    unsigned short* scr   = (unsigned short*)(ws + 83886080);    //  16,777,216 (scratch: hbuf)
    unsigned short* wh16  = (unsigned short*)(ws + 100663296);   //   8,388,608 (fp16 W_enc)
    unsigned short* wd16  = (unsigned short*)(ws + 109051904);   //   8,388,608 (fp16 W_dec)
    unsigned*       wmask = (unsigned*)(ws + 117440512);         //   1,040,384
    float*          pooled= (float*)(ws + 118480896);            //     262,144
    float*          sae   = (float*)(ws + 118743040);            //         256
    float*          gsum  = (float*)(ws + 118743296);            //  33,554,432  (optional)
    const bool use_gsum = ws_size >= (size_t)118743296 + 33554432;
    float* gptr = use_gsum ? gsum : nullptr;
    float* lnout = (float*)xh16;  // 256 KB, reuses dead xh16
    float* hbuf  = (float*)scr;   // 16 KB

    k_convert_all<<<dim3(16385), 256, 0, stream>>>(x, Wenc, Wdec, bdec, xh16, wh16, wd16, pooled);

    k_gemm_enc_256<<<dim3(DD / 256, NN / 256), 512, 0, stream>>>(xh16, wh16, benc, post, gptr);
    if (use_gsum)
        k_winsum_g<<<dim3(NWIN, BB), 256, 0, stream>>>(gsum, wmask);
    else
        k_winsum_p<<<dim3(NWIN, BB), 256, 0, stream>>>(post, wmask);
    k_votes<<<dim3(TT / 4, BB), 256, 0, stream>>>(post, wmask, pooled);
    k_gemm_recon_256<<<dim3(CC / 128, NN / 256), 512, 0, stream>>>(post, wd16, bdec, x, sae);
    k_head_ln<<<dim3(BB), 256, 0, stream>>>(pooled, lng, lnb, lnout);
    k_head_mlp<<<dim3(1024), 256, 0, stream>>>(lnout, W1, b1, hbuf);
    k_head_out<<<dim3(BB), 256, 0, stream>>>(hbuf, W2, b2, sae, out);
}